// Round 3
// baseline (48301.859 us; speedup 1.0000x reference)
//
#include <hip/hip_runtime.h>
#include <cmath>

#define BATCHN 64
#define SEQL   512
#define HD     512
#define NTAG   6
#define PAD_TAG 5
#define CHUNK  64

__device__ __forceinline__ float sigm(float x) { return 1.f / (1.f + expf(-x)); }

// ---------------- combined bias: bih + bhh ----------------
__global__ void k_bias(const float* __restrict__ a0, const float* __restrict__ c0,
                       const float* __restrict__ a1, const float* __restrict__ c1,
                       const float* __restrict__ a2, const float* __restrict__ c2,
                       const float* __restrict__ a3, const float* __restrict__ c3,
                       float* __restrict__ out) {
  int i = blockIdx.x * blockDim.x + threadIdx.x;   // 8192
  int w = i >> 11, r = i & 2047;
  float v;
  if (w == 0)      v = a0[r] + c0[r];
  else if (w == 1) v = a1[r] + c1[r];
  else if (w == 2) v = a2[r] + c2[r];
  else             v = a3[r] + c3[r];
  out[i] = v;
}

// ---------------- logits init: fc_b broadcast ----------------
__global__ void k_loginit(float* __restrict__ logits, const float* __restrict__ fcb) {
  int i = blockIdx.x * blockDim.x + threadIdx.x;   // 196608
  if (i < BATCHN * SEQL * NTAG) logits[i] = fcb[i % NTAG];
}

// ---------------- chunk GEMM: pre[r][2048] = A_row(r) . W^T + bias ----------------
// rows r = b*64 + tl; A_row: layer0 = embed[text[b,src]], layer1 = h0cat[b,src]
// src = dir ? clamp(len-1-t,0) : t
// Double-buffered LDS, single barrier per K-iter; next loads issued AFTER the
// barrier so they overlap compute and drain at the next barrier.
template<int MODE>
__global__ __launch_bounds__(256) void k_gemm_pre(
    const float* __restrict__ embed, const float* __restrict__ h0,
    const int* __restrict__ text, const int* __restrict__ lengths,
    const float* __restrict__ W, const float* __restrict__ bias,
    float* __restrict__ pre, int tbase, int dir) {
  constexpr int K = MODE ? 1024 : 256;
  constexpr int NIT = K / 16;
  __shared__ __align__(16) float As[2][16][132];
  __shared__ __align__(16) float Bs[2][16][132];
  int bx = blockIdx.x & 15;   // 16 n-tiles (N=2048)
  int by = blockIdx.x >> 4;   // 32 m-tiles (M=4096)
  int m0 = by * 128, n0 = bx * 128;
  int tid = threadIdx.x;
  int lm = tid >> 2, lk = (tid & 3) * 4;
  int rm = (tid >> 4) * 8, rn = (tid & 15) * 8;

  const float* arow0;
  const float* arow1;
  {
    int r = m0 + lm; int b = r >> 6; int t = tbase + (r & 63);
    int src = dir ? max(lengths[b] - 1 - t, 0) : t;
    arow0 = MODE ? h0 + ((size_t)b * SEQL + src) * 1024
                 : embed + (size_t)text[b * SEQL + src] * 256;
    r = m0 + lm + 64; b = r >> 6; t = tbase + (r & 63);
    src = dir ? max(lengths[b] - 1 - t, 0) : t;
    arow1 = MODE ? h0 + ((size_t)b * SEQL + src) * 1024
                 : embed + (size_t)text[b * SEQL + src] * 256;
  }

  float4 av0 = *(const float4*)(arow0 + lk);
  float4 av1 = *(const float4*)(arow1 + lk);
  float4 bv0 = *(const float4*)&W[(size_t)(n0 + lm) * K + lk];
  float4 bv1 = *(const float4*)&W[(size_t)(n0 + lm + 64) * K + lk];

  float acc[8][8] = {};
  for (int it = 0; it < NIT; ++it) {
    float (*as)[132] = As[it & 1];
    float (*bs)[132] = Bs[it & 1];
    as[lk + 0][lm] = av0.x; as[lk + 1][lm] = av0.y; as[lk + 2][lm] = av0.z; as[lk + 3][lm] = av0.w;
    as[lk + 0][lm + 64] = av1.x; as[lk + 1][lm + 64] = av1.y; as[lk + 2][lm + 64] = av1.z; as[lk + 3][lm + 64] = av1.w;
    bs[lk + 0][lm] = bv0.x; bs[lk + 1][lm] = bv0.y; bs[lk + 2][lm] = bv0.z; bs[lk + 3][lm] = bv0.w;
    bs[lk + 0][lm + 64] = bv1.x; bs[lk + 1][lm + 64] = bv1.y; bs[lk + 2][lm + 64] = bv1.z; bs[lk + 3][lm + 64] = bv1.w;
    __syncthreads();
    if (it + 1 < NIT) {
      int k0 = (it + 1) * 16;
      av0 = *(const float4*)(arow0 + k0 + lk);
      av1 = *(const float4*)(arow1 + k0 + lk);
      bv0 = *(const float4*)&W[(size_t)(n0 + lm) * K + k0 + lk];
      bv1 = *(const float4*)&W[(size_t)(n0 + lm + 64) * K + k0 + lk];
    }
#pragma unroll
    for (int k = 0; k < 16; ++k) {
      float4 a0v = *(const float4*)&as[k][rm];
      float4 a1v = *(const float4*)&as[k][rm + 4];
      float4 b0v = *(const float4*)&bs[k][rn];
      float4 b1v = *(const float4*)&bs[k][rn + 4];
      float a[8] = {a0v.x, a0v.y, a0v.z, a0v.w, a1v.x, a1v.y, a1v.z, a1v.w};
      float b[8] = {b0v.x, b0v.y, b0v.z, b0v.w, b1v.x, b1v.y, b1v.z, b1v.w};
#pragma unroll
      for (int i = 0; i < 8; ++i)
#pragma unroll
        for (int j = 0; j < 8; ++j)
          acc[i][j] = fmaf(a[i], b[j], acc[i][j]);
    }
    __syncthreads();
  }
#pragma unroll
  for (int i = 0; i < 8; ++i) {
    size_t rowb = (size_t)(m0 + rm + i) * 2048 + n0 + rn;
#pragma unroll
    for (int j = 0; j < 8; ++j)
      pre[rowb + j] = acc[i][j] + bias[n0 + rn + j];
  }
}

// ---------------- persistent 64-step LSTM chunk ----------------
// grid 256 = 2 dirs x 128 unit-blocks(4 units); block 512 = 8 waves.
// Wave (p = w&1, kq = w>>1): unit-pair {2p,2p+1}, k-quarter kq*128..+128.
// h staged to LDS each step; weights streamed (uniform float4, L2-hot);
// c-state in VGPRs; per-dir software grid barrier per step.
template<int LAYER>
__global__ __launch_bounds__(512) void k_chunk(
    const float* __restrict__ preF, const float* __restrict__ preB,
    const float* __restrict__ whhF, const float* __restrict__ whhB,
    const float* __restrict__ biasB, const int* __restrict__ lengths,
    float* __restrict__ cbuf, float* __restrict__ hbuf,
    float* __restrict__ h0cat, float* __restrict__ stage,
    const float* __restrict__ fcw, int* __restrict__ bar, int tbase) {
  __shared__ float ldsh[32768];   // h[k][b]  128KB
  __shared__ float P[4096];       // partials [16 rows][4 kq][64 b]
  __shared__ float hnS[256];      // layer-1 FC scratch

  int bid = blockIdx.x;
  int dir = bid >> 7;
  int ub  = bid & 127;
  int u0  = ub * 4;
  int tid = threadIdx.x;
  int w   = tid >> 6;
  int lane = tid & 63;
  int p   = w & 1;
  int kq  = w >> 1;

  const float* pre = dir ? preB : preF;
  const float* whh = dir ? whhB : whhF;
  float* hb_base = hbuf + dir * 65536;
  int* cnt = bar + dir;

  // weight row pointers (uniform per wave)
  const float* wr[8];
#pragma unroll
  for (int uu = 0; uu < 2; ++uu)
#pragma unroll
    for (int g = 0; g < 4; ++g)
      wr[uu * 4 + g] = whh + (size_t)(g * 512 + u0 + 2 * p + uu) * 512;

  // persistent finalize-thread state (tid<256): jl=unit-local, fb=batch
  int jl = tid >> 6;
  int fb = tid & 63;
  int jg = u0 + jl;
  float creg = 0.f, bb0 = 0.f, bb1 = 0.f, bb2 = 0.f, bb3 = 0.f;
  int lenb = 0;
  const float* prebt = pre;
  if (tid < 256) {
    creg = cbuf[dir * 32768 + jg * 64 + fb];
    lenb = lengths[fb];
    bb0 = biasB[jg]; bb1 = biasB[512 + jg]; bb2 = biasB[1024 + jg]; bb3 = biasB[1536 + jg];
    prebt = pre + (size_t)fb * 64 * 2048 + jg;
  }
  float fcr[24];
  if (LAYER == 1 && tid < 64) {
#pragma unroll
    for (int u = 0; u < 4; ++u)
#pragma unroll
      for (int tg = 0; tg < 6; ++tg)
        fcr[u * 6 + tg] = fcw[tg * 1024 + dir * 512 + u0 + u];
  }

  for (int tl = 0; tl < CHUNK; ++tl) {
    int t = tbase + tl;
    // prefetch pre-activations for finalize (hidden under stage+compute)
    float p0 = 0.f, p1 = 0.f, p2 = 0.f, p3 = 0.f;
    if (tid < 256) {
      if (dir == 1 && t >= lenb) { p0 = bb0; p1 = bb1; p2 = bb2; p3 = bb3; }
      else {
        const float* pr = prebt + (size_t)tl * 2048;
        p0 = pr[0]; p1 = pr[512]; p2 = pr[1024]; p3 = pr[1536];
      }
    }
    // stage h(t) into LDS
    {
      const float4* hsrc4 = (const float4*)(hb_base + (size_t)(t & 1) * 32768);
      float4* lds4 = (float4*)ldsh;
#pragma unroll 4
      for (int i = 0; i < 16; ++i) lds4[i * 512 + tid] = hsrc4[i * 512 + tid];
    }
    __syncthreads();
    // compute partials: 2 units x 4 gates over 128-k quarter
    {
      float acc[8] = {};
      int k0 = kq * 128;
#pragma unroll 4
      for (int kk = 0; kk < 32; ++kk) {
        int k = k0 + kk * 4;
        float h0 = ldsh[(k + 0) * 64 + lane];
        float h1 = ldsh[(k + 1) * 64 + lane];
        float h2 = ldsh[(k + 2) * 64 + lane];
        float h3 = ldsh[(k + 3) * 64 + lane];
#pragma unroll
        for (int r = 0; r < 8; ++r) {
          float4 wv = *(const float4*)(wr[r] + k);
          acc[r] = fmaf(wv.w, h3, fmaf(wv.z, h2, fmaf(wv.y, h1, fmaf(wv.x, h0, acc[r]))));
        }
      }
#pragma unroll
      for (int r = 0; r < 8; ++r) {
        int uu = r >> 2, g = r & 3;
        P[((2 * p + uu) * 4 + g) * 256 + kq * 64 + lane] = acc[r];
      }
    }
    __syncthreads();
    // finalize: gates, cell update, h writes
    if (tid < 256) {
      int base = (jl * 4) * 256 + fb;
      float s0 = P[base + 0] + P[base + 64] + P[base + 128] + P[base + 192];
      float s1 = P[base + 256] + P[base + 320] + P[base + 384] + P[base + 448];
      float s2 = P[base + 512] + P[base + 576] + P[base + 640] + P[base + 704];
      float s3 = P[base + 768] + P[base + 832] + P[base + 896] + P[base + 960];
      float gi = p0 + s0, gf = p1 + s1, gg = p2 + s2, go = p3 + s3;
      float si = sigm(gi), sf = sigm(gf), tgv = tanhf(gg), so = sigm(go);
      creg = sf * creg + si * tgv;
      float hn = so * tanhf(creg);
      hb_base[(size_t)((t + 1) & 1) * 32768 + jg * 64 + fb] = hn;
      if (LAYER == 0) {
        if (t < lenb) {
          int pos = dir ? (lenb - 1 - t) : t;
          h0cat[((size_t)fb * SEQL + pos) * 1024 + dir * 512 + jg] = hn;
        }
      } else {
        hnS[jl * 64 + fb] = hn;
      }
    }
    if (LAYER == 1) {
      __syncthreads();
      if (tid < 64) {
#pragma unroll
        for (int tg = 0; tg < 6; ++tg) {
          float s = hnS[lane] * fcr[tg] + hnS[64 + lane] * fcr[6 + tg] +
                    hnS[128 + lane] * fcr[12 + tg] + hnS[192 + lane] * fcr[18 + tg];
          stage[(size_t)(dir * 128 + ub) * 24576 + lane * 384 + tl * 6 + tg] = s;
        }
      }
    }
    // per-dir grid barrier
    __syncthreads();
    if (tl < CHUNK - 1) {
      if (tid == 0) {
        __threadfence();   // release: flush this XCD L2 (h writes) to coherence point
        __hip_atomic_fetch_add(cnt, 1, __ATOMIC_RELAXED, __HIP_MEMORY_SCOPE_AGENT);
        int target = 128 * (tl + 1);
        int it = 0;
        while (__hip_atomic_load(cnt, __ATOMIC_RELAXED, __HIP_MEMORY_SCOPE_AGENT) < target) {
          __builtin_amdgcn_s_sleep(1);
          if (++it > 500000) break;   // failsafe against scheduler pathology
        }
        __threadfence();   // acquire: invalidate stale L1/L2 lines
      }
      __syncthreads();
    }
  }
  if (tid < 256) cbuf[dir * 32768 + jg * 64 + fb] = creg;
}

// ---------------- deterministic logit reduction (per chunk) ----------------
__global__ __launch_bounds__(256) void k_redF(const float* __restrict__ stage,
                                              float* __restrict__ logits, int tbase) {
  int idx = blockIdx.x * 256 + threadIdx.x;  // 64*64*6 = 24576
  if (idx >= 64 * 64 * 6) return;
  int b = idx / 384; int r = idx % 384; int tl = r / 6, tg = r % 6;
  float s = 0.f;
#pragma unroll 8
  for (int sl = 0; sl < 128; ++sl)
    s += stage[(size_t)sl * 24576 + b * 384 + tl * 6 + tg];
  logits[((size_t)b * SEQL + tbase + tl) * 6 + tg] += s;
}

__global__ __launch_bounds__(256) void k_redB(const float* __restrict__ stage,
                                              float* __restrict__ logits,
                                              const int* __restrict__ lengths, int tbase) {
  int idx = blockIdx.x * 256 + threadIdx.x;
  if (idx >= 64 * 64 * 6) return;
  int b = idx / 384; int r = idx % 384; int tl = r / 6, tg = r % 6;
  int t = tbase + tl;
  int lenb = lengths[b];
  if (t >= lenb) return;
  float s = 0.f;
#pragma unroll 8
  for (int sl = 0; sl < 128; ++sl)
    s += stage[(size_t)(128 + sl) * 24576 + b * 384 + tl * 6 + tg];
  logits[((size_t)b * SEQL + (lenb - 1 - t)) * 6 + tg] += s;
}

// ---------------- softmax ----------------
__global__ __launch_bounds__(256) void k_softmax(const float* __restrict__ logits,
                                                 float* __restrict__ probs) {
  int pp = blockIdx.x * 256 + threadIdx.x;   // 32768 positions
  if (pp >= BATCHN * SEQL) return;
  const float* l = logits + (size_t)pp * 6;
  float mx = l[0];
#pragma unroll
  for (int k = 1; k < NTAG; ++k) mx = fmaxf(mx, l[k]);
  float e[NTAG], s = 0.f;
#pragma unroll
  for (int k = 0; k < NTAG; ++k) { e[k] = expf(l[k] - mx); s += e[k]; }
#pragma unroll
  for (int k = 0; k < NTAG; ++k) probs[(size_t)pp * 6 + k] = e[k] / s;
}

// ---------------- Viterbi (exact reference semantics) ----------------
__global__ void k_viterbi(const float* __restrict__ probs,
                          const int* __restrict__ lengths,
                          const float* __restrict__ crf_start,
                          const float* __restrict__ crf_end,
                          const float* __restrict__ crf_trans,
                          int* __restrict__ hist,
                          int* __restrict__ out) {
  int b = threadIdx.x;
  if (b >= BATCHN) return;
  const float* em = probs + (size_t)b * SEQL * NTAG;
  int* hb = hist + (size_t)b * SEQL * NTAG;
  int len = lengths[b];
  float sc[NTAG];
#pragma unroll
  for (int k = 0; k < NTAG; ++k) sc[k] = crf_start[k] + em[k];
  for (int t = 1; t < SEQL; ++t) {
    float ns[NTAG];
#pragma unroll
    for (int k = 0; k < NTAG; ++k) {
      float e = em[t * NTAG + k];
      float best = (sc[0] + crf_trans[0 * NTAG + k]) + e;
      int bi = 0;
#pragma unroll
      for (int jj = 1; jj < NTAG; ++jj) {
        float v = (sc[jj] + crf_trans[jj * NTAG + k]) + e;
        if (v > best) { best = v; bi = jj; }   // first-max tie rule
      }
      ns[k] = best;
      hb[t * NTAG + k] = bi;
    }
    if (t < len) {
#pragma unroll
      for (int k = 0; k < NTAG; ++k) sc[k] = ns[k];
    }
  }
  float bv = sc[0] + crf_end[0];
  int bl = 0;
#pragma unroll
  for (int jj = 1; jj < NTAG; ++jj) {
    float v = sc[jj] + crf_end[jj];
    if (v > bv) { bv = v; bl = jj; }
  }
  int carry = 0;
  for (int t = SEQL - 1; t >= 0; --t) {
    int back = (t < SEQL - 1) ? hb[(t + 1) * NTAG + carry] : 0;
    int tag = (t == len - 1) ? bl : back;
    out[(size_t)b * SEQL + t] = (t <= len - 1) ? tag : PAD_TAG;
    carry = tag;
  }
}

// ---------------- fallback ----------------
__global__ void k_fallback(int* __restrict__ out) {
  int i = blockIdx.x * 256 + threadIdx.x;
  if (i < BATCHN * SEQL) out[i] = PAD_TAG;
}

// ---------------- launch ----------------
extern "C" void kernel_launch(void* const* d_in, const int* in_sizes, int n_in,
                              void* d_out, int out_size, void* d_ws, size_t ws_size,
                              hipStream_t stream) {
  (void)in_sizes; (void)n_in; (void)out_size;
  const int*   text    = (const int*)d_in[0];
  const int*   lengths = (const int*)d_in[1];
  const float* embed   = (const float*)d_in[3];
  const float* wih0f = (const float*)d_in[4];
  const float* whh0f = (const float*)d_in[5];
  const float* bih0f = (const float*)d_in[6];
  const float* bhh0f = (const float*)d_in[7];
  const float* wih0b = (const float*)d_in[8];
  const float* whh0b = (const float*)d_in[9];
  const float* bih0b = (const float*)d_in[10];
  const float* bhh0b = (const float*)d_in[11];
  const float* wih1f = (const float*)d_in[12];
  const float* whh1f = (const float*)d_in[13];
  const float* bih1f = (const float*)d_in[14];
  const float* bhh1f = (const float*)d_in[15];
  const float* wih1b = (const float*)d_in[16];
  const float* whh1b = (const float*)d_in[17];
  const float* bih1b = (const float*)d_in[18];
  const float* bhh1b = (const float*)d_in[19];
  const float* fc_w  = (const float*)d_in[20];
  const float* fc_b  = (const float*)d_in[21];
  const float* crf_s = (const float*)d_in[22];
  const float* crf_e = (const float*)d_in[23];
  const float* crf_t = (const float*)d_in[24];

  // workspace layout (floats); ~229.7 MB
  const size_t need = 57417792ull * 4ull;
  if (ws_size < need) {
    k_fallback<<<128, 256, 0, stream>>>((int*)d_out);
    return;
  }
  float* ws = (float*)d_ws;
  float* h0cat  = ws;                        // 33,554,432
  float* preF   = h0cat + 33554432ull;       //  8,388,608
  float* preB   = preF  + 8388608ull;        //  8,388,608
  float* hbuf   = preB  + 8388608ull;        //    131,072  [2dir][2par][32768]
  float* cbuf   = hbuf  + 131072ull;         //     65,536
  float* biasc  = cbuf  + 65536ull;          //      8,192
  float* stagep = biasc + 8192ull;           //  6,291,456
  float* logits = stagep + 6291456ull;       //    196,608
  float* probs  = logits + 196608ull;        //    196,608
  int*   hist   = (int*)(probs + 196608ull); //    196,608 ints
  int*   bar    = (int*)(probs + 393216ull); //         64 ints

  hipMemsetAsync(bar, 0, 64 * sizeof(int), stream);
  k_bias<<<32, 256, 0, stream>>>(bih0f, bhh0f, bih0b, bhh0b, bih1f, bhh1f, bih1b, bhh1b, biasc);
  k_loginit<<<768, 256, 0, stream>>>(logits, fc_b);

  for (int L = 0; L < 2; ++L) {
    const float* whhF_ = L ? whh1f : whh0f;
    const float* whhB_ = L ? whh1b : whh0b;
    const float* wihF_ = L ? wih1f : wih0f;
    const float* wihB_ = L ? wih1b : wih0b;
    const float* biasF_ = biasc + (L ? 4096 : 0);
    const float* biasB_ = biasc + (L ? 6144 : 2048);

    hipMemsetAsync(hbuf, 0, (131072ull + 65536ull) * 4, stream);  // hbuf + cbuf

    for (int c = 0; c < 8; ++c) {
      int tbase = c * CHUNK;
      if (L == 0) {
        k_gemm_pre<0><<<512, 256, 0, stream>>>(embed, nullptr, text, lengths, wihF_, biasF_, preF, tbase, 0);
        k_gemm_pre<0><<<512, 256, 0, stream>>>(embed, nullptr, text, lengths, wihB_, biasB_, preB, tbase, 1);
        k_chunk<0><<<256, 512, 0, stream>>>(preF, preB, whhF_, whhB_, biasB_, lengths,
                                            cbuf, hbuf, h0cat, stagep, fc_w,
                                            bar + (L * 8 + c) * 2, tbase);
      } else {
        k_gemm_pre<1><<<512, 256, 0, stream>>>(nullptr, h0cat, text, lengths, wihF_, biasF_, preF, tbase, 0);
        k_gemm_pre<1><<<512, 256, 0, stream>>>(nullptr, h0cat, text, lengths, wihB_, biasB_, preB, tbase, 1);
        k_chunk<1><<<256, 512, 0, stream>>>(preF, preB, whhF_, whhB_, biasB_, lengths,
                                            cbuf, hbuf, h0cat, stagep, fc_w,
                                            bar + (L * 8 + c) * 2, tbase);
        k_redF<<<96, 256, 0, stream>>>(stagep, logits, tbase);
        k_redB<<<96, 256, 0, stream>>>(stagep, logits, lengths, tbase);
      }
    }
  }

  k_softmax<<<128, 256, 0, stream>>>(logits, probs);
  k_viterbi<<<1, 64, 0, stream>>>(probs, lengths, crf_s, crf_e, crf_t, hist, (int*)d_out);
}

// Round 4
// 32997.610 us; speedup vs baseline: 1.4638x; 1.4638x over previous
//
#include <hip/hip_runtime.h>
#include <cmath>

#define BATCHN 64
#define SEQL   512
#define HD     512
#define NTAG   6
#define PAD_TAG 5
#define CHUNK  64

__device__ __forceinline__ float sigm(float x) { return 1.f / (1.f + expf(-x)); }

// ---------------- combined bias: bih + bhh ----------------
__global__ void k_bias(const float* __restrict__ a0, const float* __restrict__ c0,
                       const float* __restrict__ a1, const float* __restrict__ c1,
                       const float* __restrict__ a2, const float* __restrict__ c2,
                       const float* __restrict__ a3, const float* __restrict__ c3,
                       float* __restrict__ out) {
  int i = blockIdx.x * blockDim.x + threadIdx.x;   // 8192
  int w = i >> 11, r = i & 2047;
  float v;
  if (w == 0)      v = a0[r] + c0[r];
  else if (w == 1) v = a1[r] + c1[r];
  else if (w == 2) v = a2[r] + c2[r];
  else             v = a3[r] + c3[r];
  out[i] = v;
}

// ---------------- logits init: fc_b broadcast ----------------
__global__ void k_loginit(float* __restrict__ logits, const float* __restrict__ fcb) {
  int i = blockIdx.x * blockDim.x + threadIdx.x;   // 196608
  if (i < BATCHN * SEQL * NTAG) logits[i] = fcb[i % NTAG];
}

// ---------------- chunk GEMM: pre[r][2048] = A_row(r) . W^T + bias ----------------
// rows r = b*64 + tl; A_row: layer0 = embed[text[b,src]], layer1 = h0cat[b,src]
// src = dir ? clamp(len-1-t,0) : t.  Double-buffered LDS, loads fly across the barrier.
template<int MODE>
__global__ __launch_bounds__(256) void k_gemm_pre(
    const float* __restrict__ embed, const float* __restrict__ h0,
    const int* __restrict__ text, const int* __restrict__ lengths,
    const float* __restrict__ W, const float* __restrict__ bias,
    float* __restrict__ pre, int tbase, int dir) {
  constexpr int K = MODE ? 1024 : 256;
  constexpr int NIT = K / 16;
  __shared__ __align__(16) float As[2][16][132];
  __shared__ __align__(16) float Bs[2][16][132];
  int bx = blockIdx.x & 15;   // 16 n-tiles (N=2048)
  int by = blockIdx.x >> 4;   // 32 m-tiles (M=4096)
  int m0 = by * 128, n0 = bx * 128;
  int tid = threadIdx.x;
  int lm = tid >> 2, lk = (tid & 3) * 4;
  int rm = (tid >> 4) * 8, rn = (tid & 15) * 8;

  const float* arow0;
  const float* arow1;
  {
    int r = m0 + lm; int b = r >> 6; int t = tbase + (r & 63);
    int src = dir ? max(lengths[b] - 1 - t, 0) : t;
    arow0 = MODE ? h0 + ((size_t)b * SEQL + src) * 1024
                 : embed + (size_t)text[b * SEQL + src] * 256;
    r = m0 + lm + 64; b = r >> 6; t = tbase + (r & 63);
    src = dir ? max(lengths[b] - 1 - t, 0) : t;
    arow1 = MODE ? h0 + ((size_t)b * SEQL + src) * 1024
                 : embed + (size_t)text[b * SEQL + src] * 256;
  }

  float4 av0 = *(const float4*)(arow0 + lk);
  float4 av1 = *(const float4*)(arow1 + lk);
  float4 bv0 = *(const float4*)&W[(size_t)(n0 + lm) * K + lk];
  float4 bv1 = *(const float4*)&W[(size_t)(n0 + lm + 64) * K + lk];

  float acc[8][8] = {};
  for (int it = 0; it < NIT; ++it) {
    float (*as)[132] = As[it & 1];
    float (*bs)[132] = Bs[it & 1];
    as[lk + 0][lm] = av0.x; as[lk + 1][lm] = av0.y; as[lk + 2][lm] = av0.z; as[lk + 3][lm] = av0.w;
    as[lk + 0][lm + 64] = av1.x; as[lk + 1][lm + 64] = av1.y; as[lk + 2][lm + 64] = av1.z; as[lk + 3][lm + 64] = av1.w;
    bs[lk + 0][lm] = bv0.x; bs[lk + 1][lm] = bv0.y; bs[lk + 2][lm] = bv0.z; bs[lk + 3][lm] = bv0.w;
    bs[lk + 0][lm + 64] = bv1.x; bs[lk + 1][lm + 64] = bv1.y; bs[lk + 2][lm + 64] = bv1.z; bs[lk + 3][lm + 64] = bv1.w;
    __syncthreads();
    if (it + 1 < NIT) {
      int k0 = (it + 1) * 16;
      av0 = *(const float4*)(arow0 + k0 + lk);
      av1 = *(const float4*)(arow1 + k0 + lk);
      bv0 = *(const float4*)&W[(size_t)(n0 + lm) * K + k0 + lk];
      bv1 = *(const float4*)&W[(size_t)(n0 + lm + 64) * K + k0 + lk];
    }
#pragma unroll
    for (int k = 0; k < 16; ++k) {
      float4 a0v = *(const float4*)&as[k][rm];
      float4 a1v = *(const float4*)&as[k][rm + 4];
      float4 b0v = *(const float4*)&bs[k][rn];
      float4 b1v = *(const float4*)&bs[k][rn + 4];
      float a[8] = {a0v.x, a0v.y, a0v.z, a0v.w, a1v.x, a1v.y, a1v.z, a1v.w};
      float b[8] = {b0v.x, b0v.y, b0v.z, b0v.w, b1v.x, b1v.y, b1v.z, b1v.w};
#pragma unroll
      for (int i = 0; i < 8; ++i)
#pragma unroll
        for (int j = 0; j < 8; ++j)
          acc[i][j] = fmaf(a[i], b[j], acc[i][j]);
    }
    __syncthreads();
  }
#pragma unroll
  for (int i = 0; i < 8; ++i) {
    size_t rowb = (size_t)(m0 + rm + i) * 2048 + n0 + rn;
#pragma unroll
    for (int j = 0; j < 8; ++j)
      pre[rowb + j] = acc[i][j] + bias[n0 + rn + j];
  }
}

// ---------------- persistent 64-step LSTM chunk ----------------
// grid 256 = 2 dirs x 128 unit-blocks(4 units); block 512 = 8 waves.
// h exchanged through COHERENT (sc0 sc1) loads/stores at the L3 coherence
// point -- no threadfence, so weights stay L1/L2-resident across steps.
// Barrier: vmcnt(0) drain per thread -> syncthreads -> relaxed atomic count.
template<int LAYER>
__global__ __launch_bounds__(512) void k_chunk(
    const float* __restrict__ preF, const float* __restrict__ preB,
    const float* __restrict__ whhF, const float* __restrict__ whhB,
    const float* __restrict__ biasB, const int* __restrict__ lengths,
    float* __restrict__ cbuf, float* __restrict__ hbuf,
    float* __restrict__ h0cat, float* __restrict__ stage,
    const float* __restrict__ fcw, int* __restrict__ bar, int tbase) {
  __shared__ float ldsh[32768];   // h[k][b]  128KB
  __shared__ float P[4096];       // partials [16 rows][4 kq][64 b]
  __shared__ float hnS[256];      // layer-1 FC scratch

  int bid = blockIdx.x;
  int dir = bid >> 7;
  int ub  = bid & 127;
  int u0  = ub * 4;
  int tid = threadIdx.x;
  int w   = tid >> 6;
  int lane = tid & 63;
  int p   = w & 1;
  int kq  = w >> 1;

  const float* pre = dir ? preB : preF;
  const float* whh = dir ? whhB : whhF;
  float* hb_base = hbuf + dir * 65536;
  int* cnt = bar + dir;

  // weight row pointers (uniform per wave)
  const float* wr[8];
#pragma unroll
  for (int uu = 0; uu < 2; ++uu)
#pragma unroll
    for (int g = 0; g < 4; ++g)
      wr[uu * 4 + g] = whh + (size_t)(g * 512 + u0 + 2 * p + uu) * 512;

  // persistent finalize-thread state (tid<256): jl=unit-local, fb=batch
  int jl = tid >> 6;
  int fb = tid & 63;
  int jg = u0 + jl;
  float creg = 0.f, bb0 = 0.f, bb1 = 0.f, bb2 = 0.f, bb3 = 0.f;
  int lenb = 0;
  const float* prebt = pre;
  if (tid < 256) {
    creg = cbuf[dir * 32768 + jg * 64 + fb];
    lenb = lengths[fb];
    bb0 = biasB[jg]; bb1 = biasB[512 + jg]; bb2 = biasB[1024 + jg]; bb3 = biasB[1536 + jg];
    prebt = pre + (size_t)fb * 64 * 2048 + jg;
  }
  float fcr[24];
  if (LAYER == 1 && tid < 64) {
#pragma unroll
    for (int u = 0; u < 4; ++u)
#pragma unroll
      for (int tg = 0; tg < 6; ++tg)
        fcr[u * 6 + tg] = fcw[tg * 1024 + dir * 512 + u0 + u];
  }

  for (int tl = 0; tl < CHUNK; ++tl) {
    int t = tbase + tl;
    // prefetch pre-activations for finalize (cached; written by earlier kernel)
    float p0 = 0.f, p1 = 0.f, p2 = 0.f, p3 = 0.f;
    if (tid < 256) {
      if (dir == 1 && t >= lenb) { p0 = bb0; p1 = bb1; p2 = bb2; p3 = bb3; }
      else {
        const float* pr = prebt + (size_t)tl * 2048;
        p0 = pr[0]; p1 = pr[512]; p2 = pr[1024]; p3 = pr[1536];
      }
    }
    // stage h(t) into LDS via coherent (sc0 sc1) loads: bypass L1/L2, read
    // the coherence point. Weights keep their L1/L2 residency.
    {
      const float4* s4 = (const float4*)(hb_base + (size_t)(t & 1) * 32768);
      float4 tmp[16];
#pragma unroll
      for (int i = 0; i < 16; ++i) {
        asm volatile("global_load_dwordx4 %0, %1, off sc0 sc1"
                     : "=v"(tmp[i]) : "v"(s4 + i * 512 + tid) : "memory");
      }
      asm volatile("s_waitcnt vmcnt(0)" ::: "memory");
      __builtin_amdgcn_sched_barrier(0);
      float4* lds4 = (float4*)ldsh;
#pragma unroll
      for (int i = 0; i < 16; ++i) lds4[i * 512 + tid] = tmp[i];
    }
    __syncthreads();
    // compute partials: 2 units x 4 gates over 128-k quarter
    {
      float acc[8] = {};
      int k0 = kq * 128;
#pragma unroll 4
      for (int kk = 0; kk < 32; ++kk) {
        int k = k0 + kk * 4;
        float h0 = ldsh[(k + 0) * 64 + lane];
        float h1 = ldsh[(k + 1) * 64 + lane];
        float h2 = ldsh[(k + 2) * 64 + lane];
        float h3 = ldsh[(k + 3) * 64 + lane];
#pragma unroll
        for (int r = 0; r < 8; ++r) {
          float4 wv = *(const float4*)(wr[r] + k);
          acc[r] = fmaf(wv.w, h3, fmaf(wv.z, h2, fmaf(wv.y, h1, fmaf(wv.x, h0, acc[r]))));
        }
      }
#pragma unroll
      for (int r = 0; r < 8; ++r) {
        int uu = r >> 2, g = r & 3;
        P[((2 * p + uu) * 4 + g) * 256 + kq * 64 + lane] = acc[r];
      }
    }
    __syncthreads();
    // finalize: gates, cell update, h writes (h via coherent store)
    if (tid < 256) {
      int base = (jl * 4) * 256 + fb;
      float s0 = P[base + 0] + P[base + 64] + P[base + 128] + P[base + 192];
      float s1 = P[base + 256] + P[base + 320] + P[base + 384] + P[base + 448];
      float s2 = P[base + 512] + P[base + 576] + P[base + 640] + P[base + 704];
      float s3 = P[base + 768] + P[base + 832] + P[base + 896] + P[base + 960];
      float gi = p0 + s0, gf = p1 + s1, gg = p2 + s2, go = p3 + s3;
      float si = sigm(gi), sf = sigm(gf), tgv = tanhf(gg), so = sigm(go);
      creg = sf * creg + si * tgv;
      float hn = so * tanhf(creg);
      {
        float* dst = hb_base + (size_t)((t + 1) & 1) * 32768 + jg * 64 + fb;
        asm volatile("global_store_dword %0, %1, off sc0 sc1"
                     :: "v"(dst), "v"(hn) : "memory");
      }
      if (LAYER == 0) {
        if (t < lenb) {
          int pos = dir ? (lenb - 1 - t) : t;
          h0cat[((size_t)fb * SEQL + pos) * 1024 + dir * 512 + jg] = hn;
        }
      } else {
        hnS[jl * 64 + fb] = hn;
      }
    }
    if (LAYER == 1) {
      __syncthreads();
      if (tid < 64) {
#pragma unroll
        for (int tg = 0; tg < 6; ++tg) {
          float s = hnS[lane] * fcr[tg] + hnS[64 + lane] * fcr[6 + tg] +
                    hnS[128 + lane] * fcr[12 + tg] + hnS[192 + lane] * fcr[18 + tg];
          stage[(size_t)(dir * 128 + ub) * 24576 + lane * 384 + tl * 6 + tg] = s;
        }
      }
    }
    // per-dir grid barrier (no cache-poisoning fences)
    if (tl < CHUNK - 1) {
      asm volatile("s_waitcnt vmcnt(0)" ::: "memory");  // own h store ack'd at coherence point
      __syncthreads();                                  // all threads' stores drained
      if (tid == 0) {
        __hip_atomic_fetch_add(cnt, 1, __ATOMIC_RELAXED, __HIP_MEMORY_SCOPE_AGENT);
        int target = 128 * (tl + 1);
        int it = 0;
        while (__hip_atomic_load(cnt, __ATOMIC_RELAXED, __HIP_MEMORY_SCOPE_AGENT) < target) {
          __builtin_amdgcn_s_sleep(2);
          if (++it > 100000) break;   // failsafe (normal skew is ~us)
        }
      }
      __syncthreads();
    }
  }
  if (tid < 256) cbuf[dir * 32768 + jg * 64 + fb] = creg;
}

// ---------------- deterministic logit reduction (per chunk) ----------------
__global__ __launch_bounds__(256) void k_redF(const float* __restrict__ stage,
                                              float* __restrict__ logits, int tbase) {
  int idx = blockIdx.x * 256 + threadIdx.x;  // 64*64*6 = 24576
  if (idx >= 64 * 64 * 6) return;
  int b = idx / 384; int r = idx % 384; int tl = r / 6, tg = r % 6;
  float s = 0.f;
#pragma unroll 8
  for (int sl = 0; sl < 128; ++sl)
    s += stage[(size_t)sl * 24576 + b * 384 + tl * 6 + tg];
  logits[((size_t)b * SEQL + tbase + tl) * 6 + tg] += s;
}

__global__ __launch_bounds__(256) void k_redB(const float* __restrict__ stage,
                                              float* __restrict__ logits,
                                              const int* __restrict__ lengths, int tbase) {
  int idx = blockIdx.x * 256 + threadIdx.x;
  if (idx >= 64 * 64 * 6) return;
  int b = idx / 384; int r = idx % 384; int tl = r / 6, tg = r % 6;
  int t = tbase + tl;
  int lenb = lengths[b];
  if (t >= lenb) return;
  float s = 0.f;
#pragma unroll 8
  for (int sl = 0; sl < 128; ++sl)
    s += stage[(size_t)(128 + sl) * 24576 + b * 384 + tl * 6 + tg];
  logits[((size_t)b * SEQL + (lenb - 1 - t)) * 6 + tg] += s;
}

// ---------------- softmax ----------------
__global__ __launch_bounds__(256) void k_softmax(const float* __restrict__ logits,
                                                 float* __restrict__ probs) {
  int pp = blockIdx.x * 256 + threadIdx.x;   // 32768 positions
  if (pp >= BATCHN * SEQL) return;
  const float* l = logits + (size_t)pp * 6;
  float mx = l[0];
#pragma unroll
  for (int k = 1; k < NTAG; ++k) mx = fmaxf(mx, l[k]);
  float e[NTAG], s = 0.f;
#pragma unroll
  for (int k = 0; k < NTAG; ++k) { e[k] = expf(l[k] - mx); s += e[k]; }
#pragma unroll
  for (int k = 0; k < NTAG; ++k) probs[(size_t)pp * 6 + k] = e[k] / s;
}

// ---------------- Viterbi (exact reference semantics) ----------------
__global__ void k_viterbi(const float* __restrict__ probs,
                          const int* __restrict__ lengths,
                          const float* __restrict__ crf_start,
                          const float* __restrict__ crf_end,
                          const float* __restrict__ crf_trans,
                          int* __restrict__ hist,
                          int* __restrict__ out) {
  int b = threadIdx.x;
  if (b >= BATCHN) return;
  const float* em = probs + (size_t)b * SEQL * NTAG;
  int* hb = hist + (size_t)b * SEQL * NTAG;
  int len = lengths[b];
  float sc[NTAG];
#pragma unroll
  for (int k = 0; k < NTAG; ++k) sc[k] = crf_start[k] + em[k];
  for (int t = 1; t < SEQL; ++t) {
    float ns[NTAG];
#pragma unroll
    for (int k = 0; k < NTAG; ++k) {
      float e = em[t * NTAG + k];
      float best = (sc[0] + crf_trans[0 * NTAG + k]) + e;
      int bi = 0;
#pragma unroll
      for (int jj = 1; jj < NTAG; ++jj) {
        float v = (sc[jj] + crf_trans[jj * NTAG + k]) + e;
        if (v > best) { best = v; bi = jj; }   // first-max tie rule
      }
      ns[k] = best;
      hb[t * NTAG + k] = bi;
    }
    if (t < len) {
#pragma unroll
      for (int k = 0; k < NTAG; ++k) sc[k] = ns[k];
    }
  }
  float bv = sc[0] + crf_end[0];
  int bl = 0;
#pragma unroll
  for (int jj = 1; jj < NTAG; ++jj) {
    float v = sc[jj] + crf_end[jj];
    if (v > bv) { bv = v; bl = jj; }
  }
  int carry = 0;
  for (int t = SEQL - 1; t >= 0; --t) {
    int back = (t < SEQL - 1) ? hb[(t + 1) * NTAG + carry] : 0;
    int tag = (t == len - 1) ? bl : back;
    out[(size_t)b * SEQL + t] = (t <= len - 1) ? tag : PAD_TAG;
    carry = tag;
  }
}

// ---------------- fallback ----------------
__global__ void k_fallback(int* __restrict__ out) {
  int i = blockIdx.x * 256 + threadIdx.x;
  if (i < BATCHN * SEQL) out[i] = PAD_TAG;
}

// ---------------- launch ----------------
extern "C" void kernel_launch(void* const* d_in, const int* in_sizes, int n_in,
                              void* d_out, int out_size, void* d_ws, size_t ws_size,
                              hipStream_t stream) {
  (void)in_sizes; (void)n_in; (void)out_size;
  const int*   text    = (const int*)d_in[0];
  const int*   lengths = (const int*)d_in[1];
  const float* embed   = (const float*)d_in[3];
  const float* wih0f = (const float*)d_in[4];
  const float* whh0f = (const float*)d_in[5];
  const float* bih0f = (const float*)d_in[6];
  const float* bhh0f = (const float*)d_in[7];
  const float* wih0b = (const float*)d_in[8];
  const float* whh0b = (const float*)d_in[9];
  const float* bih0b = (const float*)d_in[10];
  const float* bhh0b = (const float*)d_in[11];
  const float* wih1f = (const float*)d_in[12];
  const float* whh1f = (const float*)d_in[13];
  const float* bih1f = (const float*)d_in[14];
  const float* bhh1f = (const float*)d_in[15];
  const float* wih1b = (const float*)d_in[16];
  const float* whh1b = (const float*)d_in[17];
  const float* bih1b = (const float*)d_in[18];
  const float* bhh1b = (const float*)d_in[19];
  const float* fc_w  = (const float*)d_in[20];
  const float* fc_b  = (const float*)d_in[21];
  const float* crf_s = (const float*)d_in[22];
  const float* crf_e = (const float*)d_in[23];
  const float* crf_t = (const float*)d_in[24];

  // workspace layout (floats); ~229.7 MB
  const size_t need = 57417792ull * 4ull;
  if (ws_size < need) {
    k_fallback<<<128, 256, 0, stream>>>((int*)d_out);
    return;
  }
  float* ws = (float*)d_ws;
  float* h0cat  = ws;                        // 33,554,432
  float* preF   = h0cat + 33554432ull;       //  8,388,608
  float* preB   = preF  + 8388608ull;        //  8,388,608
  float* hbuf   = preB  + 8388608ull;        //    131,072  [2dir][2par][32768]
  float* cbuf   = hbuf  + 131072ull;         //     65,536
  float* biasc  = cbuf  + 65536ull;          //      8,192
  float* stagep = biasc + 8192ull;           //  6,291,456
  float* logits = stagep + 6291456ull;       //    196,608
  float* probs  = logits + 196608ull;        //    196,608
  int*   hist   = (int*)(probs + 196608ull); //    196,608 ints
  int*   bar    = (int*)(probs + 393216ull); //         64 ints

  hipMemsetAsync(bar, 0, 64 * sizeof(int), stream);
  k_bias<<<32, 256, 0, stream>>>(bih0f, bhh0f, bih0b, bhh0b, bih1f, bhh1f, bih1b, bhh1b, biasc);
  k_loginit<<<768, 256, 0, stream>>>(logits, fc_b);

  for (int L = 0; L < 2; ++L) {
    const float* whhF_ = L ? whh1f : whh0f;
    const float* whhB_ = L ? whh1b : whh0b;
    const float* wihF_ = L ? wih1f : wih0f;
    const float* wihB_ = L ? wih1b : wih0b;
    const float* biasF_ = biasc + (L ? 4096 : 0);
    const float* biasB_ = biasc + (L ? 6144 : 2048);

    hipMemsetAsync(hbuf, 0, (131072ull + 65536ull) * 4, stream);  // hbuf + cbuf

    for (int c = 0; c < 8; ++c) {
      int tbase = c * CHUNK;
      if (L == 0) {
        k_gemm_pre<0><<<512, 256, 0, stream>>>(embed, nullptr, text, lengths, wihF_, biasF_, preF, tbase, 0);
        k_gemm_pre<0><<<512, 256, 0, stream>>>(embed, nullptr, text, lengths, wihB_, biasB_, preB, tbase, 1);
        k_chunk<0><<<256, 512, 0, stream>>>(preF, preB, whhF_, whhB_, biasB_, lengths,
                                            cbuf, hbuf, h0cat, stagep, fc_w,
                                            bar + (L * 8 + c) * 2, tbase);
      } else {
        k_gemm_pre<1><<<512, 256, 0, stream>>>(nullptr, h0cat, text, lengths, wihF_, biasF_, preF, tbase, 0);
        k_gemm_pre<1><<<512, 256, 0, stream>>>(nullptr, h0cat, text, lengths, wihB_, biasB_, preB, tbase, 1);
        k_chunk<1><<<256, 512, 0, stream>>>(preF, preB, whhF_, whhB_, biasB_, lengths,
                                            cbuf, hbuf, h0cat, stagep, fc_w,
                                            bar + (L * 8 + c) * 2, tbase);
        k_redF<<<96, 256, 0, stream>>>(stagep, logits, tbase);
        k_redB<<<96, 256, 0, stream>>>(stagep, logits, lengths, tbase);
      }
    }
  }

  k_softmax<<<128, 256, 0, stream>>>(logits, probs);
  k_viterbi<<<1, 64, 0, stream>>>(probs, lengths, crf_s, crf_e, crf_t, hist, (int*)d_out);
}

// Round 5
// 19818.034 us; speedup vs baseline: 2.4373x; 1.6650x over previous
//
#include <hip/hip_runtime.h>
#include <cmath>

#define BATCHN 64
#define SEQL   512
#define HD     512
#define NTAG   6
#define PAD_TAG 5
#define CHUNK  64

__device__ __forceinline__ float sigm(float x) { return 1.f / (1.f + expf(-x)); }

// ---------------- combined bias: bih + bhh ----------------
__global__ void k_bias(const float* __restrict__ a0, const float* __restrict__ c0,
                       const float* __restrict__ a1, const float* __restrict__ c1,
                       const float* __restrict__ a2, const float* __restrict__ c2,
                       const float* __restrict__ a3, const float* __restrict__ c3,
                       float* __restrict__ out) {
  int i = blockIdx.x * blockDim.x + threadIdx.x;   // 8192
  int w = i >> 11, r = i & 2047;
  float v;
  if (w == 0)      v = a0[r] + c0[r];
  else if (w == 1) v = a1[r] + c1[r];
  else if (w == 2) v = a2[r] + c2[r];
  else             v = a3[r] + c3[r];
  out[i] = v;
}

// ---------------- logits init: fc_b broadcast ----------------
__global__ void k_loginit(float* __restrict__ logits, const float* __restrict__ fcb) {
  int i = blockIdx.x * blockDim.x + threadIdx.x;   // 196608
  if (i < BATCHN * SEQL * NTAG) logits[i] = fcb[i % NTAG];
}

// ---------------- chunk GEMM: pre[r][2048] = A_row(r) . W^T + bias ----------------
// rows r = b*64 + tl; A_row: layer0 = embed[text[b,src]], layer1 = h0cat[b,src]
// src = dir ? clamp(len-1-t,0) : t.  Double-buffered LDS; 4+4 split micro-tile
// (conflict-free LDS reads, float4 C stores).
template<int MODE>
__global__ __launch_bounds__(256) void k_gemm_pre(
    const float* __restrict__ embed, const float* __restrict__ h0,
    const int* __restrict__ text, const int* __restrict__ lengths,
    const float* __restrict__ W, const float* __restrict__ bias,
    float* __restrict__ pre, int tbase, int dir) {
  constexpr int K = MODE ? 1024 : 256;
  constexpr int NIT = K / 16;
  __shared__ __align__(16) float As[2][16][132];
  __shared__ __align__(16) float Bs[2][16][132];
  int bx = blockIdx.x & 15;   // 16 n-tiles (N=2048)
  int by = blockIdx.x >> 4;   // 32 m-tiles (M=4096)
  int m0 = by * 128, n0 = bx * 128;
  int tid = threadIdx.x;
  int lm = tid >> 2, lk = (tid & 3) * 4;
  int rm4 = (tid >> 4) * 4;   // 0..60
  int rn4 = (tid & 15) * 4;   // 0..60

  const float* arow0;
  const float* arow1;
  {
    int r = m0 + lm; int b = r >> 6; int t = tbase + (r & 63);
    int src = dir ? max(lengths[b] - 1 - t, 0) : t;
    arow0 = MODE ? h0 + ((size_t)b * SEQL + src) * 1024
                 : embed + (size_t)text[b * SEQL + src] * 256;
    r = m0 + lm + 64; b = r >> 6; t = tbase + (r & 63);
    src = dir ? max(lengths[b] - 1 - t, 0) : t;
    arow1 = MODE ? h0 + ((size_t)b * SEQL + src) * 1024
                 : embed + (size_t)text[b * SEQL + src] * 256;
  }

  float4 av0 = *(const float4*)(arow0 + lk);
  float4 av1 = *(const float4*)(arow1 + lk);
  float4 bv0 = *(const float4*)&W[(size_t)(n0 + lm) * K + lk];
  float4 bv1 = *(const float4*)&W[(size_t)(n0 + lm + 64) * K + lk];

  float acc[8][8] = {};
  for (int it = 0; it < NIT; ++it) {
    float (*as)[132] = As[it & 1];
    float (*bs)[132] = Bs[it & 1];
    as[lk + 0][lm] = av0.x; as[lk + 1][lm] = av0.y; as[lk + 2][lm] = av0.z; as[lk + 3][lm] = av0.w;
    as[lk + 0][lm + 64] = av1.x; as[lk + 1][lm + 64] = av1.y; as[lk + 2][lm + 64] = av1.z; as[lk + 3][lm + 64] = av1.w;
    bs[lk + 0][lm] = bv0.x; bs[lk + 1][lm] = bv0.y; bs[lk + 2][lm] = bv0.z; bs[lk + 3][lm] = bv0.w;
    bs[lk + 0][lm + 64] = bv1.x; bs[lk + 1][lm + 64] = bv1.y; bs[lk + 2][lm + 64] = bv1.z; bs[lk + 3][lm + 64] = bv1.w;
    __syncthreads();
    if (it + 1 < NIT) {
      int k0 = (it + 1) * 16;
      av0 = *(const float4*)(arow0 + k0 + lk);
      av1 = *(const float4*)(arow1 + k0 + lk);
      bv0 = *(const float4*)&W[(size_t)(n0 + lm) * K + k0 + lk];
      bv1 = *(const float4*)&W[(size_t)(n0 + lm + 64) * K + k0 + lk];
    }
#pragma unroll
    for (int k = 0; k < 16; ++k) {
      float4 a0v = *(const float4*)&as[k][rm4];
      float4 a1v = *(const float4*)&as[k][rm4 + 64];
      float4 b0v = *(const float4*)&bs[k][rn4];
      float4 b1v = *(const float4*)&bs[k][rn4 + 64];
      float a[8] = {a0v.x, a0v.y, a0v.z, a0v.w, a1v.x, a1v.y, a1v.z, a1v.w};
      float b[8] = {b0v.x, b0v.y, b0v.z, b0v.w, b1v.x, b1v.y, b1v.z, b1v.w};
#pragma unroll
      for (int i = 0; i < 8; ++i)
#pragma unroll
        for (int j = 0; j < 8; ++j)
          acc[i][j] = fmaf(a[i], b[j], acc[i][j]);
    }
    __syncthreads();
  }
  float4 bn0 = *(const float4*)&bias[n0 + rn4];
  float4 bn1 = *(const float4*)&bias[n0 + rn4 + 64];
#pragma unroll
  for (int i = 0; i < 8; ++i) {
    int row = m0 + rm4 + (i >> 2) * 64 + (i & 3);
    float4 o0 = {acc[i][0] + bn0.x, acc[i][1] + bn0.y, acc[i][2] + bn0.z, acc[i][3] + bn0.w};
    float4 o1 = {acc[i][4] + bn1.x, acc[i][5] + bn1.y, acc[i][6] + bn1.z, acc[i][7] + bn1.w};
    *(float4*)&pre[(size_t)row * 2048 + n0 + rn4] = o0;
    *(float4*)&pre[(size_t)row * 2048 + n0 + rn4 + 64] = o1;
  }
}

// ---------------- persistent 64-step LSTM chunk ----------------
// grid 256 = 2 dirs x 128 unit-blocks(4 units); block 512 = 8 waves.
// Whh slice (16 rows x 512) in LDS for the whole chunk; wave kq covers k-eighth
// for ALL 16 (unit,gate) rows; h read ONCE per block per step via coherent
// agent-scope loads straight into registers (no LDS h stage). Partials through
// P[16][8][64]. Barrier: coherent h store -> vmcnt(0) -> count.
template<int LAYER>
__global__ __launch_bounds__(512) void k_chunk(
    const float* __restrict__ preF, const float* __restrict__ preB,
    const float* __restrict__ whhF, const float* __restrict__ whhB,
    const float* __restrict__ biasB, const int* __restrict__ lengths,
    float* __restrict__ cbuf, float* __restrict__ hbuf,
    float* __restrict__ h0cat, float* __restrict__ stage,
    const float* __restrict__ fcw, int* __restrict__ bar, int tbase) {
  __shared__ __align__(16) float wlds[16][512];  // 32 KB weights
  __shared__ float P[16 * 512];                  // 32 KB partials [r][kq][b]
  __shared__ float preS[16 * 64];                // 4 KB pre stage [q*4+u][b]
  __shared__ float hnS[256];                     // layer-1 FC scratch

  int bid = blockIdx.x;
  int dir = bid >> 7;
  int ub  = bid & 127;
  int u0  = ub * 4;
  int tid = threadIdx.x;
  int kq  = tid >> 6;      // wave id: k-eighth (also gate-role q for tid<256)
  int lane = tid & 63;     // batch

  const float* pre = dir ? preB : preF;
  const float* whh = dir ? whhB : whhF;
  float* hb_base = hbuf + dir * 65536;
  int* cnt = bar + dir;

  // ---- load Whh slice to LDS once: row r=u*4+g -> whh[g*512+u0+u][*] ----
  {
    int r16 = tid >> 5;        // 0..15
    int kp  = tid & 31;        // 0..31 (16 floats each)
    int g = r16 & 3, u = r16 >> 2;
    const float4* src = (const float4*)(whh + (size_t)(g * 512 + u0 + u) * 512 + kp * 16);
    float4* dst = (float4*)&wlds[r16][kp * 16];
#pragma unroll
    for (int i = 0; i < 4; ++i) dst[i] = src[i];
  }

  // persistent finalize state (tid<256): jl=unit-local, fb=batch
  int jl = kq;               // for tid<256: 0..3
  int fb = lane;
  int jg = u0 + jl;
  int lenb = lengths[lane];
  float creg = 0.f;
  float4 bbq = {0.f, 0.f, 0.f, 0.f};
  const float* preb_q = pre + (size_t)fb * CHUNK * 2048;
  if (tid < 256) {
    creg = cbuf[dir * 32768 + jg * 64 + fb];
    bbq = *(const float4*)&biasB[kq * 512 + u0];   // gate q, units u0..u0+3
  }
  float fcr[24];
  if (LAYER == 1 && tid < 64) {
#pragma unroll
    for (int u = 0; u < 4; ++u)
#pragma unroll
      for (int tg = 0; tg < 6; ++tg)
        fcr[u * 6 + tg] = fcw[tg * 1024 + dir * 512 + u0 + u];
  }
  __syncthreads();   // wlds ready

  for (int tl = 0; tl < CHUNK; ++tl) {
    int t = tbase + tl;
    // ---- stage pre-activations (one float4/thread, kept in regs) ----
    float4 pv = {0.f, 0.f, 0.f, 0.f};
    if (tid < 256) {
      if (dir == 1 && t >= lenb) pv = bbq;
      else pv = *(const float4*)&preb_q[(size_t)tl * 2048 + kq * 512 + u0];
    }
    // ---- compute: 16 rows x k-eighth, h via coherent loads ----
    {
      const float* hsrc = hb_base + (size_t)(t & 1) * 32768;
      float acc[16];
#pragma unroll
      for (int r = 0; r < 16; ++r) acc[r] = 0.f;
      int k0 = kq * 64;
#pragma unroll 4
      for (int kk = 0; kk < 16; ++kk) {
        int k = k0 + kk * 4;
        float hv0 = __hip_atomic_load(&hsrc[(size_t)(k + 0) * 64 + lane], __ATOMIC_RELAXED, __HIP_MEMORY_SCOPE_AGENT);
        float hv1 = __hip_atomic_load(&hsrc[(size_t)(k + 1) * 64 + lane], __ATOMIC_RELAXED, __HIP_MEMORY_SCOPE_AGENT);
        float hv2 = __hip_atomic_load(&hsrc[(size_t)(k + 2) * 64 + lane], __ATOMIC_RELAXED, __HIP_MEMORY_SCOPE_AGENT);
        float hv3 = __hip_atomic_load(&hsrc[(size_t)(k + 3) * 64 + lane], __ATOMIC_RELAXED, __HIP_MEMORY_SCOPE_AGENT);
#pragma unroll
        for (int r = 0; r < 16; ++r) {
          float4 wv = *(const float4*)&wlds[r][k];
          acc[r] = fmaf(wv.w, hv3, fmaf(wv.z, hv2, fmaf(wv.y, hv1, fmaf(wv.x, hv0, acc[r]))));
        }
      }
#pragma unroll
      for (int r = 0; r < 16; ++r) P[r * 512 + kq * 64 + lane] = acc[r];
    }
    if (tid < 256) {
      preS[(kq * 4 + 0) * 64 + fb] = pv.x;
      preS[(kq * 4 + 1) * 64 + fb] = pv.y;
      preS[(kq * 4 + 2) * 64 + fb] = pv.z;
      preS[(kq * 4 + 3) * 64 + fb] = pv.w;
    }
    __syncthreads();
    // ---- finalize: gate sums, cell update, h stores ----
    if (tid < 256) {
      float s[4], pq[4];
#pragma unroll
      for (int g = 0; g < 4; ++g) {
        const float* pr = &P[(jl * 4 + g) * 512 + fb];
        s[g] = ((pr[0] + pr[64]) + (pr[128] + pr[192])) +
               ((pr[256] + pr[320]) + (pr[384] + pr[448]));
        pq[g] = preS[(g * 4 + jl) * 64 + fb];
      }
      float gi = pq[0] + s[0], gf = pq[1] + s[1], gg = pq[2] + s[2], go = pq[3] + s[3];
      float si = sigm(gi), sf = sigm(gf), tgv = tanhf(gg), so = sigm(go);
      creg = sf * creg + si * tgv;
      float hn = so * tanhf(creg);
      __hip_atomic_store(&hb_base[(size_t)((t + 1) & 1) * 32768 + jg * 64 + fb], hn,
                         __ATOMIC_RELAXED, __HIP_MEMORY_SCOPE_AGENT);
      if (LAYER == 0) {
        if (t < lenb) {
          int pos = dir ? (lenb - 1 - t) : t;
          h0cat[((size_t)fb * SEQL + pos) * 1024 + dir * 512 + jg] = hn;
        }
      } else {
        hnS[jl * 64 + fb] = hn;
      }
    }
    if (LAYER == 1) {
      __syncthreads();
      if (tid < 64) {
#pragma unroll
        for (int tg = 0; tg < 6; ++tg) {
          float s = hnS[lane] * fcr[tg] + hnS[64 + lane] * fcr[6 + tg] +
                    hnS[128 + lane] * fcr[12 + tg] + hnS[192 + lane] * fcr[18 + tg];
          stage[(size_t)(dir * 128 + ub) * 24576 + lane * 384 + tl * 6 + tg] = s;
        }
      }
    }
    // ---- per-dir grid barrier (h store ack'd at coherence point first) ----
    if (tl < CHUNK - 1) {
      asm volatile("s_waitcnt vmcnt(0)" ::: "memory");
      __syncthreads();
      if (tid == 0) {
        __hip_atomic_fetch_add(cnt, 1, __ATOMIC_RELAXED, __HIP_MEMORY_SCOPE_AGENT);
        int target = 128 * (tl + 1);
        int it = 0;
        while (__hip_atomic_load(cnt, __ATOMIC_RELAXED, __HIP_MEMORY_SCOPE_AGENT) < target) {
          __builtin_amdgcn_s_sleep(2);
          if (++it > 100000) break;   // failsafe against scheduler pathology
        }
      }
      __syncthreads();
    }
  }
  if (tid < 256) cbuf[dir * 32768 + jg * 64 + fb] = creg;
}

// ---------------- deterministic logit reduction (per chunk) ----------------
__global__ __launch_bounds__(256) void k_redF(const float* __restrict__ stage,
                                              float* __restrict__ logits, int tbase) {
  int idx = blockIdx.x * 256 + threadIdx.x;  // 64*64*6 = 24576
  if (idx >= 64 * 64 * 6) return;
  int b = idx / 384; int r = idx % 384; int tl = r / 6, tg = r % 6;
  float s = 0.f;
#pragma unroll 8
  for (int sl = 0; sl < 128; ++sl)
    s += stage[(size_t)sl * 24576 + b * 384 + tl * 6 + tg];
  logits[((size_t)b * SEQL + tbase + tl) * 6 + tg] += s;
}

__global__ __launch_bounds__(256) void k_redB(const float* __restrict__ stage,
                                              float* __restrict__ logits,
                                              const int* __restrict__ lengths, int tbase) {
  int idx = blockIdx.x * 256 + threadIdx.x;
  if (idx >= 64 * 64 * 6) return;
  int b = idx / 384; int r = idx % 384; int tl = r / 6, tg = r % 6;
  int t = tbase + tl;
  int lenb = lengths[b];
  if (t >= lenb) return;
  float s = 0.f;
#pragma unroll 8
  for (int sl = 0; sl < 128; ++sl)
    s += stage[(size_t)(128 + sl) * 24576 + b * 384 + tl * 6 + tg];
  logits[((size_t)b * SEQL + (lenb - 1 - t)) * 6 + tg] += s;
}

// ---------------- softmax ----------------
__global__ __launch_bounds__(256) void k_softmax(const float* __restrict__ logits,
                                                 float* __restrict__ probs) {
  int pp = blockIdx.x * 256 + threadIdx.x;   // 32768 positions
  if (pp >= BATCHN * SEQL) return;
  const float* l = logits + (size_t)pp * 6;
  float mx = l[0];
#pragma unroll
  for (int k = 1; k < NTAG; ++k) mx = fmaxf(mx, l[k]);
  float e[NTAG], s = 0.f;
#pragma unroll
  for (int k = 0; k < NTAG; ++k) { e[k] = expf(l[k] - mx); s += e[k]; }
#pragma unroll
  for (int k = 0; k < NTAG; ++k) probs[(size_t)pp * 6 + k] = e[k] / s;
}

// ---------------- Viterbi (exact reference semantics) ----------------
__global__ void k_viterbi(const float* __restrict__ probs,
                          const int* __restrict__ lengths,
                          const float* __restrict__ crf_start,
                          const float* __restrict__ crf_end,
                          const float* __restrict__ crf_trans,
                          int* __restrict__ hist,
                          int* __restrict__ out) {
  int b = threadIdx.x;
  if (b >= BATCHN) return;
  const float* em = probs + (size_t)b * SEQL * NTAG;
  int* hb = hist + (size_t)b * SEQL * NTAG;
  int len = lengths[b];
  float sc[NTAG];
#pragma unroll
  for (int k = 0; k < NTAG; ++k) sc[k] = crf_start[k] + em[k];
  for (int t = 1; t < SEQL; ++t) {
    float ns[NTAG];
#pragma unroll
    for (int k = 0; k < NTAG; ++k) {
      float e = em[t * NTAG + k];
      float best = (sc[0] + crf_trans[0 * NTAG + k]) + e;
      int bi = 0;
#pragma unroll
      for (int jj = 1; jj < NTAG; ++jj) {
        float v = (sc[jj] + crf_trans[jj * NTAG + k]) + e;
        if (v > best) { best = v; bi = jj; }   // first-max tie rule
      }
      ns[k] = best;
      hb[t * NTAG + k] = bi;
    }
    if (t < len) {
#pragma unroll
      for (int k = 0; k < NTAG; ++k) sc[k] = ns[k];
    }
  }
  float bv = sc[0] + crf_end[0];
  int bl = 0;
#pragma unroll
  for (int jj = 1; jj < NTAG; ++jj) {
    float v = sc[jj] + crf_end[jj];
    if (v > bv) { bv = v; bl = jj; }
  }
  int carry = 0;
  for (int t = SEQL - 1; t >= 0; --t) {
    int back = (t < SEQL - 1) ? hb[(t + 1) * NTAG + carry] : 0;
    int tag = (t == len - 1) ? bl : back;
    out[(size_t)b * SEQL + t] = (t <= len - 1) ? tag : PAD_TAG;
    carry = tag;
  }
}

// ---------------- fallback ----------------
__global__ void k_fallback(int* __restrict__ out) {
  int i = blockIdx.x * 256 + threadIdx.x;
  if (i < BATCHN * SEQL) out[i] = PAD_TAG;
}

// ---------------- launch ----------------
extern "C" void kernel_launch(void* const* d_in, const int* in_sizes, int n_in,
                              void* d_out, int out_size, void* d_ws, size_t ws_size,
                              hipStream_t stream) {
  (void)in_sizes; (void)n_in; (void)out_size;
  const int*   text    = (const int*)d_in[0];
  const int*   lengths = (const int*)d_in[1];
  const float* embed   = (const float*)d_in[3];
  const float* wih0f = (const float*)d_in[4];
  const float* whh0f = (const float*)d_in[5];
  const float* bih0f = (const float*)d_in[6];
  const float* bhh0f = (const float*)d_in[7];
  const float* wih0b = (const float*)d_in[8];
  const float* whh0b = (const float*)d_in[9];
  const float* bih0b = (const float*)d_in[10];
  const float* bhh0b = (const float*)d_in[11];
  const float* wih1f = (const float*)d_in[12];
  const float* whh1f = (const float*)d_in[13];
  const float* bih1f = (const float*)d_in[14];
  const float* bhh1f = (const float*)d_in[15];
  const float* wih1b = (const float*)d_in[16];
  const float* whh1b = (const float*)d_in[17];
  const float* bih1b = (const float*)d_in[18];
  const float* bhh1b = (const float*)d_in[19];
  const float* fc_w  = (const float*)d_in[20];
  const float* fc_b  = (const float*)d_in[21];
  const float* crf_s = (const float*)d_in[22];
  const float* crf_e = (const float*)d_in[23];
  const float* crf_t = (const float*)d_in[24];

  // workspace layout (floats); ~229.7 MB
  const size_t need = 57417792ull * 4ull;
  if (ws_size < need) {
    k_fallback<<<128, 256, 0, stream>>>((int*)d_out);
    return;
  }
  float* ws = (float*)d_ws;
  float* h0cat  = ws;                        // 33,554,432
  float* preF   = h0cat + 33554432ull;       //  8,388,608
  float* preB   = preF  + 8388608ull;        //  8,388,608
  float* hbuf   = preB  + 8388608ull;        //    131,072  [2dir][2par][32768]
  float* cbuf   = hbuf  + 131072ull;         //     65,536
  float* biasc  = cbuf  + 65536ull;          //      8,192
  float* stagep = biasc + 8192ull;           //  6,291,456
  float* logits = stagep + 6291456ull;       //    196,608
  float* probs  = logits + 196608ull;        //    196,608
  int*   hist   = (int*)(probs + 196608ull); //    196,608 ints
  int*   bar    = (int*)(probs + 393216ull); //         64 ints

  hipMemsetAsync(bar, 0, 64 * sizeof(int), stream);
  k_bias<<<32, 256, 0, stream>>>(bih0f, bhh0f, bih0b, bhh0b, bih1f, bhh1f, bih1b, bhh1b, biasc);
  k_loginit<<<768, 256, 0, stream>>>(logits, fc_b);

  for (int L = 0; L < 2; ++L) {
    const float* whhF_ = L ? whh1f : whh0f;
    const float* whhB_ = L ? whh1b : whh0b;
    const float* wihF_ = L ? wih1f : wih0f;
    const float* wihB_ = L ? wih1b : wih0b;
    const float* biasF_ = biasc + (L ? 4096 : 0);
    const float* biasB_ = biasc + (L ? 6144 : 2048);

    hipMemsetAsync(hbuf, 0, (131072ull + 65536ull) * 4, stream);  // hbuf + cbuf

    for (int c = 0; c < 8; ++c) {
      int tbase = c * CHUNK;
      if (L == 0) {
        k_gemm_pre<0><<<512, 256, 0, stream>>>(embed, nullptr, text, lengths, wihF_, biasF_, preF, tbase, 0);
        k_gemm_pre<0><<<512, 256, 0, stream>>>(embed, nullptr, text, lengths, wihB_, biasB_, preB, tbase, 1);
        k_chunk<0><<<256, 512, 0, stream>>>(preF, preB, whhF_, whhB_, biasB_, lengths,
                                            cbuf, hbuf, h0cat, stagep, fc_w,
                                            bar + (L * 8 + c) * 2, tbase);
      } else {
        k_gemm_pre<1><<<512, 256, 0, stream>>>(nullptr, h0cat, text, lengths, wihF_, biasF_, preF, tbase, 0);
        k_gemm_pre<1><<<512, 256, 0, stream>>>(nullptr, h0cat, text, lengths, wihB_, biasB_, preB, tbase, 1);
        k_chunk<1><<<256, 512, 0, stream>>>(preF, preB, whhF_, whhB_, biasB_, lengths,
                                            cbuf, hbuf, h0cat, stagep, fc_w,
                                            bar + (L * 8 + c) * 2, tbase);
        k_redF<<<96, 256, 0, stream>>>(stagep, logits, tbase);
        k_redB<<<96, 256, 0, stream>>>(stagep, logits, lengths, tbase);
      }
    }
  }

  k_softmax<<<128, 256, 0, stream>>>(logits, probs);
  k_viterbi<<<1, 64, 0, stream>>>(probs, lengths, crf_s, crf_e, crf_t, hist, (int*)d_out);
}